// Round 1
// baseline (1284.898 us; speedup 1.0000x reference)
//
#include <hip/hip_runtime.h>
#include <math.h>

// Problem constants (DigitCaps routing)
#define B_SZ 64
#define P_SZ 2048
#define PD   16
#define N_SZ 32
#define D_SZ 32
#define ND   1024            // N_SZ * D_SZ
#define PC   16              // p per block
#define BC   16              // b per block
#define NPC  (P_SZ / PC)     // 128 p-chunks
#define NBC  (B_SZ / BC)     // 4  b-chunks

__device__ __forceinline__ float dot4(const float4 a, const float4 b) {
    return a.x * b.x + a.y * b.y + a.z * b.z + a.w * b.w;
}

// One routing step, fused:
//   pred[b,p,n,d] = sum_q w[p,n,d,q] * x[b,p,q]       (recomputed, never stored)
//   MODE==0: c = 1/32 (softmax of zero logits)
//   MODE==1: b_new = agreement        (b_in == 0, skip load), c = softmax_n(b_new)
//   MODE==2: b_new = b_io + agreement,                  c = softmax_n(b_new)
//   s_part[pc][b][n,d] = sum_{p in chunk} c * pred
// Thread t owns nd = 4t..4t+3 (n = t>>3, 8 lanes per n — all in one wave).
template <int MODE>
__global__ __launch_bounds__(256) void fused_pass(
    const float* __restrict__ x, const float* __restrict__ w,
    const float* __restrict__ v_in, float* __restrict__ b_io,
    float* __restrict__ s_part)
{
    const int t  = threadIdx.x;
    const int pc = blockIdx.x;   // 0..NPC-1
    const int bc = blockIdx.y;   // 0..NBC-1
    const int p0 = pc * PC, b0 = bc * BC;

    __shared__ float4 xs4[BC * PC * PD / 4];  // [bl][pl][q/4], 16 KiB
    __shared__ float  sden[4];                // per-wave softmax partials

    // Stage x tile: contiguous 256-float segment per b
    {
        const float4* xg = (const float4*)x;
        #pragma unroll
        for (int i = 0; i < 4; ++i) {
            int f   = t + 256 * i;      // 0..1023
            int bl  = f >> 6;
            int rem = f & 63;
            xs4[f] = xg[((size_t)(b0 + bl) * P_SZ * PD + (size_t)p0 * PD) / 4 + rem];
        }
    }
    __syncthreads();

    float4 sacc[BC];
    #pragma unroll
    for (int i = 0; i < BC; ++i) sacc[i] = make_float4(0.f, 0.f, 0.f, 0.f);

    const int n  = t >> 3;
    const int wv = t >> 6;

    for (int pl = 0; pl < PC; ++pl) {
        const int p = p0 + pl;
        // Per-thread W slice: w[p][4t..4t+3][0..15] = 64 floats, register-resident
        float4 w4[16];
        const float4* wp = (const float4*)(w + (size_t)p * ND * PD) + (size_t)t * 16;
        #pragma unroll
        for (int k = 0; k < 16; ++k) w4[k] = wp[k];

        for (int bl = 0; bl < BC; ++bl) {
            const int b = b0 + bl;
            float4 xv[4];
            #pragma unroll
            for (int m = 0; m < 4; ++m) xv[m] = xs4[(bl * PC + pl) * 4 + m];

            float4 pr;
            pr.x = dot4(w4[0],  xv[0]) + dot4(w4[1],  xv[1]) + dot4(w4[2],  xv[2]) + dot4(w4[3],  xv[3]);
            pr.y = dot4(w4[4],  xv[0]) + dot4(w4[5],  xv[1]) + dot4(w4[6],  xv[2]) + dot4(w4[7],  xv[3]);
            pr.z = dot4(w4[8],  xv[0]) + dot4(w4[9],  xv[1]) + dot4(w4[10], xv[2]) + dot4(w4[11], xv[3]);
            pr.w = dot4(w4[12], xv[0]) + dot4(w4[13], xv[1]) + dot4(w4[14], xv[2]) + dot4(w4[15], xv[3]);

            float c;
            if (MODE == 0) {
                c = 1.0f / 32.0f;
            } else {
                // agreement = sum_d pred * v  (reduce over 8 lanes of this n)
                const float4 vv = *(const float4*)(v_in + (size_t)b * ND + t * 4);
                float ap = dot4(pr, vv);
                ap += __shfl_xor(ap, 1);
                ap += __shfl_xor(ap, 2);
                ap += __shfl_xor(ap, 4);
                const size_t bidx = ((size_t)b * P_SZ + p) * N_SZ + n;
                float bnew = (MODE == 1) ? ap : (b_io[bidx] + ap);
                if ((t & 7) == 0) b_io[bidx] = bnew;

                // softmax over n (32 values, b is O(1) -> no max subtraction needed)
                float e  = __expf(bnew);
                float ps = e;                      // 8 lanes/n duplicate -> wave sum = 8*sum_n
                ps += __shfl_xor(ps, 8);
                ps += __shfl_xor(ps, 16);
                ps += __shfl_xor(ps, 32);
                __syncthreads();                   // protect sden reuse
                if ((t & 63) == 0) sden[wv] = ps;
                __syncthreads();
                float den = (sden[0] + sden[1] + sden[2] + sden[3]) * 0.125f;
                c = e / den;
            }
            sacc[bl].x += c * pr.x;
            sacc[bl].y += c * pr.y;
            sacc[bl].z += c * pr.z;
            sacc[bl].w += c * pr.w;
        }
    }

    float4* sp = (float4*)s_part;
    #pragma unroll
    for (int bl = 0; bl < BC; ++bl) {
        sp[(size_t)pc * (B_SZ * ND / 4) + (size_t)(b0 + bl) * (ND / 4) + t] = sacc[bl];
    }
}

// s[b][nd] = sum_pc s_part[pc][b][nd]; v = squash(s) over d per (b,n)
__global__ __launch_bounds__(256) void reduce_squash(
    const float* __restrict__ s_part, float* __restrict__ dst)
{
    const int t = threadIdx.x;
    const int b = blockIdx.x;
    const float4* sp = (const float4*)s_part;
    float4 s = make_float4(0.f, 0.f, 0.f, 0.f);
    for (int pcid = 0; pcid < NPC; ++pcid) {
        float4 v = sp[(size_t)pcid * (B_SZ * ND / 4) + (size_t)b * (ND / 4) + t];
        s.x += v.x; s.y += v.y; s.z += v.z; s.w += v.w;
    }
    float sq = dot4(s, s);
    sq += __shfl_xor(sq, 1);
    sq += __shfl_xor(sq, 2);
    sq += __shfl_xor(sq, 4);
    const float f = sq / ((1.0f + sq) * sqrtf(sq + 1e-7f));
    float4 o = make_float4(f * s.x, f * s.y, f * s.z, f * s.w);
    ((float4*)dst)[(size_t)b * (ND / 4) + t] = o;
}

extern "C" void kernel_launch(void* const* d_in, const int* in_sizes, int n_in,
                              void* d_out, int out_size, void* d_ws, size_t ws_size,
                              hipStream_t stream)
{
    const float* x = (const float*)d_in[0];   // (B,P,pD)
    const float* w = (const float*)d_in[1];   // (P,N,D,pD)
    float* out = (float*)d_out;               // (B,N,D)
    float* ws  = (float*)d_ws;

    float* v_buf  = ws;                              // 65,536 floats
    float* b_log  = ws + 65536;                      // 4,194,304 floats
    float* s_part = ws + 65536 + 4194304;            // 8,388,608 floats  (~48.3 MiB total)

    dim3 fg(NPC, NBC), fb(256);
    dim3 rg(B_SZ), rb(256);

    // v1 = ws(b=0)
    fused_pass<0><<<fg, fb, 0, stream>>>(x, w, nullptr, nullptr, s_part);
    reduce_squash<<<rg, rb, 0, stream>>>(s_part, v_buf);
    // b1 = agr(v1); v2 = ws(b1)
    fused_pass<1><<<fg, fb, 0, stream>>>(x, w, v_buf, b_log, s_part);
    reduce_squash<<<rg, rb, 0, stream>>>(s_part, v_buf);
    // b2 = b1 + agr(v2); v3 = ws(b2)
    fused_pass<2><<<fg, fb, 0, stream>>>(x, w, v_buf, b_log, s_part);
    reduce_squash<<<rg, rb, 0, stream>>>(s_part, v_buf);
    // b3 = b2 + agr(v3); out = ws(b3)
    fused_pass<2><<<fg, fb, 0, stream>>>(x, w, v_buf, b_log, s_part);
    reduce_squash<<<rg, rb, 0, stream>>>(s_part, out);
}

// Round 2
// 946.620 us; speedup vs baseline: 1.3574x; 1.3574x over previous
//
#include <hip/hip_runtime.h>
#include <math.h>

// Problem constants (DigitCaps routing)
#define B_SZ 64
#define P_SZ 2048
#define PD   16
#define N_SZ 32
#define D_SZ 32
#define ND   1024            // N_SZ * D_SZ
#define PC   16              // p per block
#define BC   16              // b per block
#define NPC  (P_SZ / PC)     // 128 p-chunks
#define NBC  (B_SZ / BC)     // 4  b-chunks

__device__ __forceinline__ float dot4(const float4 a, const float4 b) {
    return a.x * b.x + a.y * b.y + a.z * b.z + a.w * b.w;
}

// One routing step, fused. Thread t owns nd = 4t..4t+3 (n = t>>3, d = (t&7)*4).
//   pred[b,p,n,d] = sum_q w[p,n,d,q] * x[b,p,q]   (recomputed, never stored)
//   MODE==0: c = 1/32; MODE==1: b = agr; MODE==2: b += agr; c = softmax_n(b)
//   s_part[pc][b][nd] = sum_{p in chunk} c * pred
// Softmax batched over 8 b's per barrier: 2 barriers/pl (vs 32 in round 1).
template <int MODE>
__global__ __launch_bounds__(256, 2) void fused_pass(
    const float* __restrict__ x, const float* __restrict__ w,
    const float* __restrict__ v_in, float* __restrict__ b_io,
    float* __restrict__ s_part)
{
    const int t    = threadIdx.x;
    const int pc   = blockIdx.x;   // 0..NPC-1
    const int pcswz = (pc & 7) * (NPC / 8) + (pc >> 3); // XCD-aware spread (perf only)
    const int bc   = blockIdx.y;   // 0..NBC-1
    const int p0   = pcswz * PC, b0 = bc * BC;
    const int n    = t >> 3;
    const int wv   = t >> 6;
    const int lane = t & 63;

    __shared__ float4 vs4[BC * (ND / 4)];  // 64 KiB: v[b0..b0+15][all nd]
    __shared__ float  sden[2][32];         // [half][j*4 + wave] softmax partials

    if (MODE != 0) {
        const float4* vg = (const float4*)v_in;
        #pragma unroll
        for (int i = 0; i < BC; ++i) {
            const int idx = t + 256 * i;
            vs4[idx] = vg[(size_t)(b0 + (idx >> 8)) * (ND / 4) + (idx & 255)];
        }
        __syncthreads();
    }

    float4 sacc[BC];
    #pragma unroll
    for (int i = 0; i < BC; ++i) sacc[i] = make_float4(0.f, 0.f, 0.f, 0.f);

    for (int pl = 0; pl < PC; ++pl) {
        const int p = p0 + pl;
        // Per-thread W slice: w[p][4t..4t+3][0..15] = 64 floats, register-resident
        float4 w4[16];
        {
            const float4* wp = (const float4*)(w + (size_t)p * (ND * PD)) + (size_t)t * 16;
            #pragma unroll
            for (int k = 0; k < 16; ++k) w4[k] = wp[k];
        }

        if (MODE == 0) {
            #pragma unroll
            for (int bl = 0; bl < BC; ++bl) {
                // thread-uniform x read (scalar path); L1/L2 resident
                const float4* xp = (const float4*)(x + ((size_t)(b0 + bl) * P_SZ + p) * PD);
                const float4 xv0 = xp[0], xv1 = xp[1], xv2 = xp[2], xv3 = xp[3];
                float4 pr;
                pr.x = dot4(w4[0],  xv0) + dot4(w4[1],  xv1) + dot4(w4[2],  xv2) + dot4(w4[3],  xv3);
                pr.y = dot4(w4[4],  xv0) + dot4(w4[5],  xv1) + dot4(w4[6],  xv2) + dot4(w4[7],  xv3);
                pr.z = dot4(w4[8],  xv0) + dot4(w4[9],  xv1) + dot4(w4[10], xv2) + dot4(w4[11], xv3);
                pr.w = dot4(w4[12], xv0) + dot4(w4[13], xv1) + dot4(w4[14], xv2) + dot4(w4[15], xv3);
                const float c = 1.0f / 32.0f;
                sacc[bl].x += c * pr.x; sacc[bl].y += c * pr.y;
                sacc[bl].z += c * pr.z; sacc[bl].w += c * pr.w;
            }
        } else {
            #pragma unroll
            for (int h = 0; h < 2; ++h) {
                float4 pr[8];
                float  ap[8], ee[8], bold[8];

                if (MODE == 2) {
                    #pragma unroll
                    for (int j = 0; j < 8; ++j) {
                        const int b = b0 + h * 8 + j;
                        bold[j] = b_io[((size_t)b * P_SZ + p) * N_SZ + n];
                    }
                }
                #pragma unroll
                for (int j = 0; j < 8; ++j) {
                    const int bl = h * 8 + j;
                    const float4* xp = (const float4*)(x + ((size_t)(b0 + bl) * P_SZ + p) * PD);
                    const float4 xv0 = xp[0], xv1 = xp[1], xv2 = xp[2], xv3 = xp[3];
                    pr[j].x = dot4(w4[0],  xv0) + dot4(w4[1],  xv1) + dot4(w4[2],  xv2) + dot4(w4[3],  xv3);
                    pr[j].y = dot4(w4[4],  xv0) + dot4(w4[5],  xv1) + dot4(w4[6],  xv2) + dot4(w4[7],  xv3);
                    pr[j].z = dot4(w4[8],  xv0) + dot4(w4[9],  xv1) + dot4(w4[10], xv2) + dot4(w4[11], xv3);
                    pr[j].w = dot4(w4[12], xv0) + dot4(w4[13], xv1) + dot4(w4[14], xv2) + dot4(w4[15], xv3);
                    const float4 vv = vs4[bl * (ND / 4) + t];
                    ap[j] = dot4(pr[j], vv);
                }
                // agreement: reduce over 8 d-lanes (bits 0-2), 8-way ILP
                #pragma unroll
                for (int j = 0; j < 8; ++j) {
                    ap[j] += __shfl_xor(ap[j], 1);
                    ap[j] += __shfl_xor(ap[j], 2);
                    ap[j] += __shfl_xor(ap[j], 4);
                }
                #pragma unroll
                for (int j = 0; j < 8; ++j) {
                    const int b = b0 + h * 8 + j;
                    const size_t bidx = ((size_t)b * P_SZ + p) * N_SZ + n;
                    const float bnew = (MODE == 1) ? ap[j] : (bold[j] + ap[j]);
                    if ((t & 7) == 0) b_io[bidx] = bnew;
                    ee[j] = __expf(bnew);
                }
                // per-wave softmax partial: sum over the wave's 8 n's (bits 3-5)
                #pragma unroll
                for (int j = 0; j < 8; ++j) {
                    float ps = ee[j];
                    ps += __shfl_xor(ps, 8);
                    ps += __shfl_xor(ps, 16);
                    ps += __shfl_xor(ps, 32);
                    ap[j] = ps;  // uniform across wave now
                }
                if (lane == 0) {
                    #pragma unroll
                    for (int j = 0; j < 8; ++j) sden[h][j * 4 + wv] = ap[j];
                }
                __syncthreads();   // buffer sden[h]; reuse at pl+1 fenced by other half's barrier
                #pragma unroll
                for (int j = 0; j < 8; ++j) {
                    const int bl = h * 8 + j;
                    const float4 dd = *(const float4*)&sden[h][j * 4];
                    // exact softmax: den = sum over all 32 n (no 1/8 fudge — round-1 bug fixed)
                    const float c = ee[j] * __builtin_amdgcn_rcpf(dd.x + dd.y + dd.z + dd.w);
                    sacc[bl].x += c * pr[j].x; sacc[bl].y += c * pr[j].y;
                    sacc[bl].z += c * pr[j].z; sacc[bl].w += c * pr[j].w;
                }
            }
        }
    }

    float4* sp = (float4*)s_part;
    #pragma unroll
    for (int bl = 0; bl < BC; ++bl) {
        sp[(size_t)pcswz * (B_SZ * ND / 4) + (size_t)(b0 + bl) * (ND / 4) + t] = sacc[bl];
    }
}

// s[b][nd] = sum_pc s_part[pc][b][nd]; v = squash(s) over d per (b,n)
__global__ __launch_bounds__(256) void reduce_squash(
    const float* __restrict__ s_part, float* __restrict__ dst)
{
    const int t = threadIdx.x;
    const int b = blockIdx.x;
    const float4* sp = (const float4*)s_part;
    float4 s = make_float4(0.f, 0.f, 0.f, 0.f);
    for (int pcid = 0; pcid < NPC; ++pcid) {
        float4 v = sp[(size_t)pcid * (B_SZ * ND / 4) + (size_t)b * (ND / 4) + t];
        s.x += v.x; s.y += v.y; s.z += v.z; s.w += v.w;
    }
    float sq = dot4(s, s);
    sq += __shfl_xor(sq, 1);
    sq += __shfl_xor(sq, 2);
    sq += __shfl_xor(sq, 4);
    const float f = sq / ((1.0f + sq) * sqrtf(sq + 1e-7f));
    float4 o = make_float4(f * s.x, f * s.y, f * s.z, f * s.w);
    ((float4*)dst)[(size_t)b * (ND / 4) + t] = o;
}

extern "C" void kernel_launch(void* const* d_in, const int* in_sizes, int n_in,
                              void* d_out, int out_size, void* d_ws, size_t ws_size,
                              hipStream_t stream)
{
    const float* x = (const float*)d_in[0];   // (B,P,pD)
    const float* w = (const float*)d_in[1];   // (P,N,D,pD)
    float* out = (float*)d_out;               // (B,N,D)
    float* ws  = (float*)d_ws;

    float* v_buf  = ws;                              // 65,536 floats
    float* b_log  = ws + 65536;                      // 4,194,304 floats
    float* s_part = ws + 65536 + 4194304;            // 8,388,608 floats

    dim3 fg(NPC, NBC), fb(256);
    dim3 rg(B_SZ), rb(256);

    fused_pass<0><<<fg, fb, 0, stream>>>(x, w, nullptr, nullptr, s_part);
    reduce_squash<<<rg, rb, 0, stream>>>(s_part, v_buf);
    fused_pass<1><<<fg, fb, 0, stream>>>(x, w, v_buf, b_log, s_part);
    reduce_squash<<<rg, rb, 0, stream>>>(s_part, v_buf);
    fused_pass<2><<<fg, fb, 0, stream>>>(x, w, v_buf, b_log, s_part);
    reduce_squash<<<rg, rb, 0, stream>>>(s_part, v_buf);
    fused_pass<2><<<fg, fb, 0, stream>>>(x, w, v_buf, b_log, s_part);
    reduce_squash<<<rg, rb, 0, stream>>>(s_part, out);
}

// Round 3
// 748.611 us; speedup vs baseline: 1.7164x; 1.2645x over previous
//
#include <hip/hip_runtime.h>
#include <math.h>

// DigitCaps routing constants
#define B_SZ 64
#define P_SZ 2048
#define PD   16
#define N_SZ 32
#define D_SZ 32
#define ND   1024            // N_SZ * D_SZ
#define PC   16              // p per fused block
#define BC   16              // b per fused block
#define NPC  (P_SZ / PC)     // 128
#define NBC  (B_SZ / BC)     // 4

typedef _Float16 half2_t __attribute__((ext_vector_type(2)));

__device__ __forceinline__ float dot2acc(unsigned a, unsigned b, float acc) {
#if __has_builtin(__builtin_amdgcn_fdot2)
    return __builtin_amdgcn_fdot2(__builtin_bit_cast(half2_t, a),
                                  __builtin_bit_cast(half2_t, b), acc, false);
#else
    const half2_t ha = __builtin_bit_cast(half2_t, a);
    const half2_t hb = __builtin_bit_cast(half2_t, b);
    return acc + (float)ha[0] * (float)hb[0] + (float)ha[1] * (float)hb[1];
#endif
}

__device__ __forceinline__ unsigned packh2(float a, float b) {
    half2_t h; h[0] = (_Float16)a; h[1] = (_Float16)b;
    return __builtin_bit_cast(unsigned, h);
}

__device__ __forceinline__ float dot4(const float4 a, const float4 b) {
    return a.x * b.x + a.y * b.y + a.z * b.z + a.w * b.w;
}

// w (P,ND,PD) fp32 -> w2 f16, chunked so fused thread t reads coalesced:
// uint4 W[k] at w2u4[(p*8+k)*256 + t] holds w[p][4t + (k>>1)][(k&1)*8 .. +7]
// as 4 f16-pairs. Reads here are coalesced float4; writes are 8B scattered
// within a 32 KiB window (L2-absorbed, one-time cost).
__global__ __launch_bounds__(256) void repack_w(const float4* __restrict__ w4,
                                                unsigned* __restrict__ w2) {
    const size_t g = (size_t)blockIdx.x * 256 + threadIdx.x;  // < 8388608
    const float4 f4 = w4[g];
    const size_t f = g * 4;                 // float index
    const int p  = (int)(f >> 14);          // /(ND*PD)
    const int nd = (int)((f >> 4) & 1023);
    const int q0 = (int)(f & 15);           // 0,4,8,12
    const int t  = nd >> 2, r = nd & 3;
    const int k  = r * 2 + (q0 >> 3);
    const int jp = (q0 & 7) >> 1;           // 0 or 2 (uint-pair slot)
    const size_t du = (((size_t)p * 8 + k) * 256 + t) * 4 + jp;
    uint2 val = { packh2(f4.x, f4.y), packh2(f4.z, f4.w) };
    *(uint2*)(w2 + du) = val;
}

// x (B,P,PD) fp32 -> x2 f16 pairs, layout preserved: x2u4[(b*P+p)*2 + half]
__global__ __launch_bounds__(256) void repack_x(const float4* __restrict__ x4,
                                                uint4* __restrict__ x2) {
    const size_t g = (size_t)blockIdx.x * 256 + threadIdx.x;  // < 262144
    const float4 a = x4[g * 2], b = x4[g * 2 + 1];
    uint4 o;
    o.x = packh2(a.x, a.y); o.y = packh2(a.z, a.w);
    o.z = packh2(b.x, b.y); o.w = packh2(b.z, b.w);
    x2[g] = o;
}

__device__ __forceinline__ float4 predict(const uint4* W, const unsigned* X) {
    float s; float4 pr;
    s = dot2acc(W[0].x, X[0], 0.f); s = dot2acc(W[0].y, X[1], s);
    s = dot2acc(W[0].z, X[2], s);   s = dot2acc(W[0].w, X[3], s);
    s = dot2acc(W[1].x, X[4], s);   s = dot2acc(W[1].y, X[5], s);
    s = dot2acc(W[1].z, X[6], s);   s = dot2acc(W[1].w, X[7], s);
    pr.x = s;
    s = dot2acc(W[2].x, X[0], 0.f); s = dot2acc(W[2].y, X[1], s);
    s = dot2acc(W[2].z, X[2], s);   s = dot2acc(W[2].w, X[3], s);
    s = dot2acc(W[3].x, X[4], s);   s = dot2acc(W[3].y, X[5], s);
    s = dot2acc(W[3].z, X[6], s);   s = dot2acc(W[3].w, X[7], s);
    pr.y = s;
    s = dot2acc(W[4].x, X[0], 0.f); s = dot2acc(W[4].y, X[1], s);
    s = dot2acc(W[4].z, X[2], s);   s = dot2acc(W[4].w, X[3], s);
    s = dot2acc(W[5].x, X[4], s);   s = dot2acc(W[5].y, X[5], s);
    s = dot2acc(W[5].z, X[6], s);   s = dot2acc(W[5].w, X[7], s);
    pr.z = s;
    s = dot2acc(W[6].x, X[0], 0.f); s = dot2acc(W[6].y, X[1], s);
    s = dot2acc(W[6].z, X[2], s);   s = dot2acc(W[6].w, X[3], s);
    s = dot2acc(W[7].x, X[4], s);   s = dot2acc(W[7].y, X[5], s);
    s = dot2acc(W[7].z, X[6], s);   s = dot2acc(W[7].w, X[7], s);
    pr.w = s;
    return pr;
}

// One routing step. Thread t owns nd = 4t..4t+3 (n = t>>3).
// MODE==0: c=1/32; MODE==1: b=agr; MODE==2: b+=agr; c=softmax_n(b)
template <int MODE>
__global__ __launch_bounds__(256, 2) void fused_pass(
    const uint4* __restrict__ x2, const uint4* __restrict__ w2,
    const float* __restrict__ v_in, float* __restrict__ b_io,
    float* __restrict__ s_part)
{
    const int t     = threadIdx.x;
    const int pc    = blockIdx.x;
    const int pcswz = (pc & 7) * (NPC / 8) + (pc >> 3);
    const int bc    = blockIdx.y;
    const int p0    = pcswz * PC, b0 = bc * BC;
    const int n     = t >> 3;
    const int wv    = t >> 6;
    const int lane  = t & 63;

    __shared__ float sden[2][32];

    float4 vreg[BC];
    if (MODE != 0) {
        #pragma unroll
        for (int bl = 0; bl < BC; ++bl)
            vreg[bl] = ((const float4*)v_in)[(size_t)(b0 + bl) * (ND / 4) + t];
    }

    float4 sacc[BC];
    #pragma unroll
    for (int i = 0; i < BC; ++i) sacc[i] = make_float4(0.f, 0.f, 0.f, 0.f);

    for (int pl = 0; pl < PC; ++pl) {
        const int p = p0 + pl;
        uint4 W[8];
        {
            const uint4* wp = w2 + (size_t)p * (8 * 256) + t;
            #pragma unroll
            for (int k = 0; k < 8; ++k) W[k] = wp[k * 256];
        }

        if (MODE == 0) {
            #pragma unroll
            for (int bl = 0; bl < BC; ++bl) {
                const uint4* xp = x2 + ((size_t)(b0 + bl) * P_SZ + p) * 2;
                const uint4 xa = xp[0], xb = xp[1];
                const unsigned X[8] = {xa.x, xa.y, xa.z, xa.w, xb.x, xb.y, xb.z, xb.w};
                const float4 pr = predict(W, X);
                sacc[bl].x += pr.x * (1.0f / 32.0f);
                sacc[bl].y += pr.y * (1.0f / 32.0f);
                sacc[bl].z += pr.z * (1.0f / 32.0f);
                sacc[bl].w += pr.w * (1.0f / 32.0f);
            }
        } else {
            #pragma unroll
            for (int h = 0; h < 2; ++h) {
                float4 pr[8];
                float  ap[8], ee[8], bold[8];

                if (MODE == 2) {
                    #pragma unroll
                    for (int j = 0; j < 8; ++j) {
                        const int b = b0 + h * 8 + j;
                        bold[j] = b_io[((size_t)b * P_SZ + p) * N_SZ + n];
                    }
                }
                #pragma unroll
                for (int j = 0; j < 8; ++j) {
                    const int bl = h * 8 + j;
                    const uint4* xp = x2 + ((size_t)(b0 + bl) * P_SZ + p) * 2;
                    const uint4 xa = xp[0], xb = xp[1];
                    const unsigned X[8] = {xa.x, xa.y, xa.z, xa.w, xb.x, xb.y, xb.z, xb.w};
                    pr[j] = predict(W, X);
                    ap[j] = dot4(pr[j], vreg[bl]);
                }
                #pragma unroll
                for (int j = 0; j < 8; ++j) {
                    ap[j] += __shfl_xor(ap[j], 1);
                    ap[j] += __shfl_xor(ap[j], 2);
                    ap[j] += __shfl_xor(ap[j], 4);
                }
                #pragma unroll
                for (int j = 0; j < 8; ++j) {
                    const int b = b0 + h * 8 + j;
                    const size_t bidx = ((size_t)b * P_SZ + p) * N_SZ + n;
                    const float bnew = (MODE == 1) ? ap[j] : (bold[j] + ap[j]);
                    if ((t & 7) == 0) b_io[bidx] = bnew;
                    ee[j] = __expf(bnew);
                }
                #pragma unroll
                for (int j = 0; j < 8; ++j) {
                    float ps = ee[j];
                    ps += __shfl_xor(ps, 8);
                    ps += __shfl_xor(ps, 16);
                    ps += __shfl_xor(ps, 32);
                    ap[j] = ps;
                }
                if (lane == 0) {
                    #pragma unroll
                    for (int j = 0; j < 8; ++j) sden[h][j * 4 + wv] = ap[j];
                }
                __syncthreads();  // parity-buffered sden: safe across pl (see r2)
                #pragma unroll
                for (int j = 0; j < 8; ++j) {
                    const int bl = h * 8 + j;
                    const float4 dd = *(const float4*)&sden[h][j * 4];
                    const float c = ee[j] * __builtin_amdgcn_rcpf(dd.x + dd.y + dd.z + dd.w);
                    sacc[bl].x += c * pr[j].x; sacc[bl].y += c * pr[j].y;
                    sacc[bl].z += c * pr[j].z; sacc[bl].w += c * pr[j].w;
                }
            }
        }
    }

    float4* sp = (float4*)s_part;
    #pragma unroll
    for (int bl = 0; bl < BC; ++bl) {
        sp[(size_t)pcswz * (B_SZ * ND / 4) + (size_t)(b0 + bl) * (ND / 4) + t] = sacc[bl];
    }
}

// s[b][nd] = sum_pc s_part[pc][b][nd]; v = squash(s) over d per (b,n)
__global__ __launch_bounds__(256) void reduce_squash(
    const float* __restrict__ s_part, float* __restrict__ dst)
{
    const int t = threadIdx.x;
    const int b = blockIdx.x;
    const float4* sp = (const float4*)s_part;
    float4 s = make_float4(0.f, 0.f, 0.f, 0.f);
    for (int pcid = 0; pcid < NPC; ++pcid) {
        float4 v = sp[(size_t)pcid * (B_SZ * ND / 4) + (size_t)b * (ND / 4) + t];
        s.x += v.x; s.y += v.y; s.z += v.z; s.w += v.w;
    }
    float sq = dot4(s, s);
    sq += __shfl_xor(sq, 1);
    sq += __shfl_xor(sq, 2);
    sq += __shfl_xor(sq, 4);
    const float f = sq / ((1.0f + sq) * sqrtf(sq + 1e-7f));
    ((float4*)dst)[(size_t)b * (ND / 4) + t] =
        make_float4(f * s.x, f * s.y, f * s.z, f * s.w);
}

extern "C" void kernel_launch(void* const* d_in, const int* in_sizes, int n_in,
                              void* d_out, int out_size, void* d_ws, size_t ws_size,
                              hipStream_t stream)
{
    const float* x = (const float*)d_in[0];   // (B,P,pD)
    const float* w = (const float*)d_in[1];   // (P,N,D,pD)
    float* out = (float*)d_out;               // (B,N,D)
    float* ws  = (float*)d_ws;

    float*    v_buf  = ws;                                   // 65,536 f
    float*    b_log  = ws + 65536;                           // 4,194,304 f
    float*    s_part = ws + 65536 + 4194304;                 // 8,388,608 f
    unsigned* w2     = (unsigned*)(ws + 12648448);           // 16,777,216 u32 (64 MiB)
    uint4*    x2     = (uint4*)(ws + 12648448 + 16777216);   // 4 MiB
    // total ws use ≈ 122 MiB

    // One-time f16 repack (amortized over 4 passes)
    repack_w<<<dim3(32768), dim3(256), 0, stream>>>((const float4*)w, w2);
    repack_x<<<dim3(1024),  dim3(256), 0, stream>>>((const float4*)x, (uint4*)x2);

    dim3 fg(NPC, NBC), fb(256);
    dim3 rg(B_SZ), rb(256);

    fused_pass<0><<<fg, fb, 0, stream>>>(x2, (const uint4*)w2, nullptr, nullptr, s_part);
    reduce_squash<<<rg, rb, 0, stream>>>(s_part, v_buf);
    fused_pass<1><<<fg, fb, 0, stream>>>(x2, (const uint4*)w2, v_buf, b_log, s_part);
    reduce_squash<<<rg, rb, 0, stream>>>(s_part, v_buf);
    fused_pass<2><<<fg, fb, 0, stream>>>(x2, (const uint4*)w2, v_buf, b_log, s_part);
    reduce_squash<<<rg, rb, 0, stream>>>(s_part, v_buf);
    fused_pass<2><<<fg, fb, 0, stream>>>(x2, (const uint4*)w2, v_buf, b_log, s_part);
    reduce_squash<<<rg, rb, 0, stream>>>(s_part, out);
}